// Round 7
// baseline (2825.041 us; speedup 1.0000x reference)
//
#include <hip/hip_runtime.h>
#include <hip/hip_bf16.h>
#include <math.h>

#define B_ 2048
#define L_ 32
#define V_ 1024
#define E_ 256
#define H_ 512
#define DEC_T_ 7

typedef unsigned short u16;
using bf16x8 = __attribute__((ext_vector_type(8))) short;
using f32x4  = __attribute__((ext_vector_type(4))) float;

__device__ __forceinline__ u16 f2b(float f) {
  union { float f; unsigned int i; } x; x.f = f;
  unsigned int r = x.i + 0x7FFFu + ((x.i >> 16) & 1u);
  return (u16)(r >> 16);
}
__device__ __forceinline__ float b2f(u16 u) {
  union { unsigned int i; float f; } x; x.i = ((unsigned int)u) << 16; return x.f;
}
__device__ __forceinline__ float sigm(float x) { return 1.f / (1.f + __expf(-x)); }
__device__ __forceinline__ float tanhfast(float x) {
  const float xx = fminf(fmaxf(x, -15.f), 15.f);
  const float e = __expf(2.f * xx);
  return (e - 1.f) / (e + 1.f);
}

// ---------------------------------------------------------------------------
// Transposed fused LSTM gate GEMM, all-bf16 operands, register-prefetch
// double buffer. G^T[j][m] = Wr[j]·act[m]; j gate-interleaved (n*4+gate) so
// each lane's 4 C-regs are the 4 gates of one hidden unit -> cell in epilogue.
// act = [emb_b[tok] | h_in] (K=E+H) or h_in (K=H). h bf16, c fp32.
// ---------------------------------------------------------------------------
struct LP {
  const int* feat;      // token for row m at feat[m*L_]; null => decoder
  const u16* emb;       // V x E bf16
  const u16* h_in;      // B x H bf16
  const u16* W;         // 2048 x K bf16, gate-interleaved rows
  const float* bsum;    // 2048 fp32
  u16* h_out;           // B x H bf16
  float* c;             // B x H fp32 in-place
  int K;
};

__launch_bounds__(256)
__global__ void lstm_mfma_k(LP p0, LP p1) {
  LP p = blockIdx.z ? p1 : p0;
  __shared__ u16 Wt[128 * 40];
  __shared__ u16 At[128 * 40];
  const int tid = threadIdx.x;
  const int lane = tid & 63, wave = tid >> 6;
  const int wr = wave & 1, wc = wave >> 1;
  const int j0 = blockIdx.x * 128, m0 = blockIdx.y * 128;
  const int lr = lane & 15, lk = (lane >> 4) * 8;
  const int crow = tid >> 2, ckc = (tid & 3) * 8;

  f32x4 acc[4][4] = {};
  uint4 wv[2], av[2];

  auto ldg = [&](int k0) {
#pragma unroll
    for (int cc = 0; cc < 2; ++cc) {
      const int r = crow + cc * 64;
      const int k = k0 + ckc;
      wv[cc] = *(const uint4*)(p.W + (long)(j0 + r) * p.K + k);
      const u16* src;
      if (p.feat) {
        if (k < E_) src = p.emb + p.feat[(m0 + r) * L_] * E_ + k;
        else        src = p.h_in + (m0 + r) * H_ + (k - E_);
      } else {
        src = p.h_in + (m0 + r) * H_ + k;
      }
      av[cc] = *(const uint4*)src;
    }
  };

  ldg(0);
  for (int k0 = 0; k0 < p.K; k0 += 32) {
    __syncthreads();
#pragma unroll
    for (int cc = 0; cc < 2; ++cc) {
      const int r = crow + cc * 64;
      *(uint4*)(Wt + r * 40 + ckc) = wv[cc];
      *(uint4*)(At + r * 40 + ckc) = av[cc];
    }
    __syncthreads();
    if (k0 + 32 < p.K) ldg(k0 + 32);
    bf16x8 af[4], bfr[4];
#pragma unroll
    for (int t = 0; t < 4; ++t) {
      af[t]  = *(const bf16x8*)(Wt + (wr * 64 + t * 16 + lr) * 40 + lk);
      bfr[t] = *(const bf16x8*)(At + (wc * 64 + t * 16 + lr) * 40 + lk);
    }
#pragma unroll
    for (int i = 0; i < 4; ++i)
#pragma unroll
      for (int j = 0; j < 4; ++j)
        acc[i][j] = __builtin_amdgcn_mfma_f32_16x16x32_bf16(af[i], bfr[j], acc[i][j], 0, 0, 0);
  }

#pragma unroll
  for (int i = 0; i < 4; ++i) {
    const int jb = j0 + wr * 64 + i * 16 + (lane >> 4) * 4;
    const int n = jb >> 2;
    const float4 bs = *(const float4*)(p.bsum + jb);
#pragma unroll
    for (int j = 0; j < 4; ++j) {
      const int m = m0 + wc * 64 + j * 16 + lr;
      const int idx = m * H_ + n;
      const float gi = acc[i][j][0] + bs.x;
      const float gf = acc[i][j][1] + bs.y;
      const float gg = acc[i][j][2] + bs.z;
      const float go = acc[i][j][3] + bs.w;
      const float cn = sigm(gf) * p.c[idx] + sigm(gi) * tanhfast(gg);
      const float hn = sigm(go) * tanhfast(cn);
      p.c[idx] = cn;
      p.h_out[idx] = f2b(hn);
    }
  }
}

// ---------------------------------------------------------------------------
// Transposed output GEMM (all-bf16, prefetch): C^T[j][m] = W[j]·act[m]+bias.
// Lane's 4 C-regs = 4 consecutive j at one m -> float4 stores.
// mode 0: heads (j<512 -> out0=mu, else out1=lv; act0/act1 per j-block)
// mode 1: ff batched (row m -> b=m&2047, t=m>>11; store out0[b*7168+t*1024+j])
// ---------------------------------------------------------------------------
struct OP {
  const u16* W;        // N x K bf16
  const u16* act0;     // M x K bf16
  const u16* act1;     // heads only
  const float* bias0; const float* bias1;
  float* out0; float* out1;
  int K; int mode;
};

__launch_bounds__(256)
__global__ void outT_mfma_k(OP p) {
  __shared__ u16 Wt[128 * 40];
  __shared__ u16 At[128 * 40];
  const int tid = threadIdx.x;
  const int lane = tid & 63, wave = tid >> 6;
  const int wr = wave & 1, wc = wave >> 1;
  const int j0 = blockIdx.x * 128, m0 = blockIdx.y * 128;
  const int lr = lane & 15, lk = (lane >> 4) * 8;
  const int crow = tid >> 2, ckc = (tid & 3) * 8;
  const u16* act = (p.mode == 0 && j0 >= 512) ? p.act1 : p.act0;

  f32x4 acc[4][4] = {};
  uint4 wv[2], av[2];

  auto ldg = [&](int k0) {
#pragma unroll
    for (int cc = 0; cc < 2; ++cc) {
      const int r = crow + cc * 64;
      const int k = k0 + ckc;
      wv[cc] = *(const uint4*)(p.W + (long)(j0 + r) * p.K + k);
      av[cc] = *(const uint4*)(act + (long)(m0 + r) * p.K + k);
    }
  };

  ldg(0);
  for (int k0 = 0; k0 < p.K; k0 += 32) {
    __syncthreads();
#pragma unroll
    for (int cc = 0; cc < 2; ++cc) {
      const int r = crow + cc * 64;
      *(uint4*)(Wt + r * 40 + ckc) = wv[cc];
      *(uint4*)(At + r * 40 + ckc) = av[cc];
    }
    __syncthreads();
    if (k0 + 32 < p.K) ldg(k0 + 32);
    bf16x8 af[4], bfr[4];
#pragma unroll
    for (int t = 0; t < 4; ++t) {
      af[t]  = *(const bf16x8*)(Wt + (wr * 64 + t * 16 + lr) * 40 + lk);
      bfr[t] = *(const bf16x8*)(At + (wc * 64 + t * 16 + lr) * 40 + lk);
    }
#pragma unroll
    for (int i = 0; i < 4; ++i)
#pragma unroll
      for (int j = 0; j < 4; ++j)
        acc[i][j] = __builtin_amdgcn_mfma_f32_16x16x32_bf16(af[i], bfr[j], acc[i][j], 0, 0, 0);
  }

#pragma unroll
  for (int i = 0; i < 4; ++i) {
    const int j = j0 + wr * 64 + i * 16 + (lane >> 4) * 4;
    float4 bv;
    if (p.mode == 0) bv = (j < 512) ? *(const float4*)(p.bias0 + j)
                                    : *(const float4*)(p.bias1 + (j - 512));
    else             bv = *(const float4*)(p.bias0 + j);
#pragma unroll
    for (int jj = 0; jj < 4; ++jj) {
      const int m = m0 + wc * 64 + jj * 16 + lr;
      float4 v;
      v.x = acc[i][jj][0] + bv.x; v.y = acc[i][jj][1] + bv.y;
      v.z = acc[i][jj][2] + bv.z; v.w = acc[i][jj][3] + bv.w;
      float* dst;
      if (p.mode == 0) {
        dst = (j < 512) ? (p.out0 + (long)m * H_ + j)
                        : (p.out1 + (long)m * H_ + (j - 512));
      } else {
        const int b = m & (B_ - 1), t = m >> 11;
        dst = p.out0 + (long)b * (DEC_T_ * V_) + t * V_ + j;
      }
      *(float4*)dst = v;
    }
  }
}

// ---- prep kernels ----------------------------------------------------------
__global__ void prep_gates_k(const float* Wih, const float* Whh,
                             const float* b1, const float* b2,
                             u16* Wout, float* bsum, int KI, int K) {
  const int j = blockIdx.y;
  const int k = blockIdx.x * 256 + threadIdx.x;
  const int worig = (j & 3) * H_ + (j >> 2);
  const float v = (k < KI) ? Wih[worig * KI + k] : Whh[worig * H_ + (k - KI)];
  Wout[(long)j * K + k] = f2b(v);
  if (k == 0) bsum[j] = b1[worig] + b2[worig];
}

__global__ void cast_k(const float* s, u16* d) {
  const int i = blockIdx.x * 256 + threadIdx.x;
  d[i] = f2b(s[i]);
}

__global__ void init_k(float* a, float* b, u16* c, u16* d) {
  const int i = blockIdx.x * 256 + threadIdx.x;
  a[i] = 0.f; b[i] = 0.f; c[i] = 0; d[i] = 0;
}

__global__ void cast_feat_k(const int* f, float* o) {
  const int i = blockIdx.x * 256 + threadIdx.x;
  o[i] = b2f(f2b((float)f[i]));
}

// LN over concat(hf,hb) (bf16 in) -> two bf16 affine outputs (mu-LN, lv-LN)
__global__ void ln_k(const u16* hf, const u16* hb,
                     const float* mug, const float* mub,
                     const float* lvg, const float* lvb,
                     u16* Amu, u16* Alv) {
  const int b = blockIdx.x, t = threadIdx.x;
  float x[4], s = 0.f, sq = 0.f;
#pragma unroll
  for (int j = 0; j < 4; ++j) {
    const int k = t + 256 * j;
    const float v = (k < H_) ? b2f(hf[b * H_ + k]) : b2f(hb[b * H_ + (k - H_)]);
    x[j] = v; s += v; sq += v * v;
  }
#pragma unroll
  for (int off = 32; off; off >>= 1) {
    s += __shfl_down(s, off);
    sq += __shfl_down(sq, off);
  }
  __shared__ float ss[4], ssq[4];
  if ((t & 63) == 0) { ss[t >> 6] = s; ssq[t >> 6] = sq; }
  __syncthreads();
  const float S = ss[0] + ss[1] + ss[2] + ss[3];
  const float SQ = ssq[0] + ssq[1] + ssq[2] + ssq[3];
  const float m = S * (1.f / 1024.f);
  const float var = SQ * (1.f / 1024.f) - m * m;
  const float rs = rsqrtf(var + 1e-5f);
#pragma unroll
  for (int j = 0; j < 4; ++j) {
    const int k = t + 256 * j;
    const float y = (x[j] - m) * rs;
    Amu[(long)b * 1024 + k] = f2b(y * mug[k] + mub[k]);
    Alv[(long)b * 1024 + k] = f2b(y * lvg[k] + lvb[k]);
  }
}

__global__ void z_k(const float* mu, const float* lv, const float* eps,
                    u16* zh, float* zc) {
  const int i = blockIdx.x * 256 + threadIdx.x;
  const float z = mu[i] + __expf(0.5f * lv[i]) * eps[i];
  zh[i] = f2b(z);
  zc[i] = z;
}

extern "C" void kernel_launch(void* const* d_in, const int* in_sizes, int n_in,
                              void* d_out, int out_size, void* d_ws, size_t ws_size,
                              hipStream_t stream) {
  const int*   features = (const int*)d_in[0];
  const float* eps      = (const float*)d_in[1];
  const float* emb      = (const float*)d_in[2];
  const float* eWih_f   = (const float*)d_in[3];
  const float* eWhh_f   = (const float*)d_in[4];
  const float* ebih_f   = (const float*)d_in[5];
  const float* ebhh_f   = (const float*)d_in[6];
  const float* eWih_b   = (const float*)d_in[7];
  const float* eWhh_b   = (const float*)d_in[8];
  const float* ebih_b   = (const float*)d_in[9];
  const float* ebhh_b   = (const float*)d_in[10];
  const float* dWhh     = (const float*)d_in[12];
  const float* dbih     = (const float*)d_in[13];
  const float* dbhh     = (const float*)d_in[14];
  const float* mu_ln_g  = (const float*)d_in[15];
  const float* mu_ln_b  = (const float*)d_in[16];
  const float* mu_W     = (const float*)d_in[17];
  const float* mu_b     = (const float*)d_in[18];
  const float* lv_ln_g  = (const float*)d_in[19];
  const float* lv_ln_b  = (const float*)d_in[20];
  const float* lv_W     = (const float*)d_in[21];
  const float* lv_b     = (const float*)d_in[22];
  const float* ff_W     = (const float*)d_in[23];
  const float* ff_b     = (const float*)d_in[24];

  // d_out FP32: [features 65536 | features_hat 14680064 | mu 1048576 | lv 1048576]
  float* of = (float*)d_out;
  float* o_feat = of;
  float* o_fh   = of + (B_ * L_);
  float* o_mu   = o_fh + (long)B_ * DEC_T_ * V_;
  float* o_lv   = o_mu + (long)B_ * H_;

  const int NA = B_ * H_;   // 1,048,576
  // ws layout (~35.6 MB):
  float* c_f  = (float*)d_ws;          // enc fwd c; later A_lv(u16); later dec c
  float* c_b  = c_f + NA;              // enc bwd c; later A_mu(u16)
  u16* pool   = (u16*)(c_b + NA);      // 8 bf16 h slots of NA each
  u16* s0 = pool;                      // enc fwd ping; later z-h
  u16* s1 = pool + 1 * NA;             // enc fwd pong; hcat[0]
  u16* s2 = pool + 2 * NA;             // enc bwd ping; hcat[1]
  u16* s3 = pool + 3 * NA;             // enc bwd pong; hcat[2]
  u16* hcat = s1;                      // contiguous 7 slots s1..s7
  u16* Wenc_f = pool + 8 * NA;         // 2048*768
  u16* Wenc_b = Wenc_f + 2048 * 768;
  u16* Wdec   = Wenc_b + 2048 * 768;   // 2048*512
  u16* Wff    = Wdec + 2048 * 512;     // 1024*512
  u16* Whead  = Wff + 1024 * 512;      // 1024*1024 (mu rows 0..511, lv 512..1023)
  u16* emb_b  = Whead + 1024 * 1024;   // V*E
  float* bsum_f = (float*)(emb_b + V_ * E_);
  float* bsum_b = bsum_f + 2048;
  float* bsum_d = bsum_b + 2048;
  u16* A_mu = (u16*)c_b;               // B x 1024 bf16 (after enc c dead)
  u16* A_lv = (u16*)c_f;

  cast_feat_k<<<dim3(B_ * L_ / 256), dim3(256), 0, stream>>>(features, o_feat);
  init_k<<<dim3(NA / 256), dim3(256), 0, stream>>>(c_f, c_b, s0, s2);

  // ---- weight prep ---------------------------------------------------------
  prep_gates_k<<<dim3(3, 2048), dim3(256), 0, stream>>>(eWih_f, eWhh_f, ebih_f, ebhh_f, Wenc_f, bsum_f, E_, E_ + H_);
  prep_gates_k<<<dim3(3, 2048), dim3(256), 0, stream>>>(eWih_b, eWhh_b, ebih_b, ebhh_b, Wenc_b, bsum_b, E_, E_ + H_);
  prep_gates_k<<<dim3(2, 2048), dim3(256), 0, stream>>>(nullptr, dWhh, dbih, dbhh, Wdec, bsum_d, 0, H_);
  cast_k<<<dim3(1024 * 512 / 256), dim3(256), 0, stream>>>(ff_W, Wff);
  cast_k<<<dim3(512 * 1024 / 256), dim3(256), 0, stream>>>(mu_W, Whead);
  cast_k<<<dim3(512 * 1024 / 256), dim3(256), 0, stream>>>(lv_W, Whead + 512 * 1024);
  cast_k<<<dim3(V_ * E_ / 256), dim3(256), 0, stream>>>(emb, emb_b);

  // ---- encoder: 32 dual-direction fused MFMA steps -------------------------
  for (int s = 0; s < L_; ++s) {
    LP pf{}, pb{};
    pf.feat = features + s;              pb.feat = features + (L_ - 1 - s);
    pf.emb = emb_b;                      pb.emb = emb_b;
    pf.h_in  = (s & 1) ? s1 : s0;        pb.h_in  = (s & 1) ? s3 : s2;
    pf.h_out = (s & 1) ? s0 : s1;        pb.h_out = (s & 1) ? s2 : s3;
    pf.W = Wenc_f;  pf.bsum = bsum_f;    pb.W = Wenc_b;  pb.bsum = bsum_b;
    pf.c = c_f;                          pb.c = c_b;
    pf.K = E_ + H_;                      pb.K = E_ + H_;
    lstm_mfma_k<<<dim3(16, 16, 2), dim3(256), 0, stream>>>(pf, pb);
  }
  // 32 (even) steps: fwd final h in s0, bwd final h in s2.

  // ---- LN (bf16 normalized copies) + combined mu/lv head -------------------
  ln_k<<<dim3(B_), dim3(256), 0, stream>>>(s0, s2, mu_ln_g, mu_ln_b, lv_ln_g, lv_ln_b, A_mu, A_lv);
  {
    OP ph{};
    ph.W = Whead;
    ph.act0 = A_mu; ph.act1 = A_lv;
    ph.bias0 = mu_b; ph.bias1 = lv_b;
    ph.out0 = o_mu; ph.out1 = o_lv;
    ph.K = 1024; ph.mode = 0;
    outT_mfma_k<<<dim3(8, 16), dim3(256), 0, stream>>>(ph);
  }
  // z: bf16 h seed into s0 (dead), fp32 c into c_f (A_lv dead after head GEMM)
  z_k<<<dim3(NA / 256), dim3(256), 0, stream>>>(o_mu, o_lv, eps, s0, c_f);

  // ---- decoder: 7 fused MFMA steps into contiguous hcat --------------------
  for (int t = 0; t < DEC_T_; ++t) {
    LP pg{};
    pg.feat = nullptr; pg.emb = nullptr;
    pg.h_in  = (t == 0) ? s0 : (hcat + (long)(t - 1) * NA);
    pg.h_out = hcat + (long)t * NA;
    pg.W = Wdec; pg.bsum = bsum_d;
    pg.c = c_f;
    pg.K = H_;
    lstm_mfma_k<<<dim3(16, 16, 1), dim3(256), 0, stream>>>(pg, pg);
  }

  // ---- ONE batched ff projection over all 7 steps --------------------------
  {
    OP pf{};
    pf.W = Wff;
    pf.act0 = hcat; pf.act1 = nullptr;
    pf.bias0 = ff_b; pf.bias1 = nullptr;
    pf.out0 = o_fh; pf.out1 = nullptr;
    pf.K = H_; pf.mode = 1;
    outT_mfma_k<<<dim3(8, DEC_T_ * B_ / 128), dim3(256), 0, stream>>>(pf);
  }
}